// Round 4
// baseline (186.546 us; speedup 1.0000x reference)
//
#include <hip/hip_runtime.h>
#include <math.h>

// RoPE+SDPA attention. Round 3: attn restructure — swapped QK^T (per-lane
// row softmax, 2 shfls/tile), exp2 folding, register-double-buffered K
// prefetch, setprio around MFMA. Other kernels unchanged from round 2.
// B=8 L=1024 H=8 Dh=64 HID=512.

#define BB 8
#define LL 1024
#define HH 8
#define DH 64
#define HID 512

typedef __bf16 bf16x8 __attribute__((ext_vector_type(8)));
typedef float f32x4 __attribute__((ext_vector_type(4)));
typedef unsigned short u16x8 __attribute__((ext_vector_type(8)));
typedef unsigned short u16x4 __attribute__((ext_vector_type(4)));

__device__ inline unsigned short f2bf(float f) {
    union { float f; unsigned u; } v; v.f = f;
    unsigned r = v.u + 0x7fffu + ((v.u >> 16) & 1u);
    return (unsigned short)(r >> 16);
}
__device__ inline float bf2f(unsigned short s) {
    union { unsigned u; float f; } v; v.u = ((unsigned)s) << 16;
    return v.f;
}

#define GLOAD_LDS16(g, l) __builtin_amdgcn_global_load_lds( \
    (const __attribute__((address_space(1))) unsigned int*)(g), \
    (__attribute__((address_space(3))) unsigned int*)(l), 16, 0, 0)

// ---------------- RoPE table ----------------
__global__ void rope_table_kernel(float* __restrict__ cos_t, float* __restrict__ sin_t) {
    int idx = blockIdx.x * blockDim.x + threadIdx.x;
    if (idx >= LL * 32) return;
    int l = idx >> 5, j = idx & 31;
    float inv = exp2f(-(float)j * (13.287712379549449f / 32.0f));
    float th = (float)l * inv;
    cos_t[idx] = cosf(th);
    sin_t[idx] = sinf(th);
}

// ---------------- fp32 -> bf16 convert (x and the four W's) ----------------
__global__ __launch_bounds__(256) void convert_kernel(
    const float* __restrict__ x, const float* __restrict__ Wq,
    const float* __restrict__ Wk, const float* __restrict__ Wv,
    const float* __restrict__ Wo,
    unsigned short* __restrict__ xb, unsigned short* __restrict__ wqb,
    unsigned short* __restrict__ wkb, unsigned short* __restrict__ wvb,
    unsigned short* __restrict__ wob)
{
    int blk = blockIdx.x;
    const float* s; unsigned short* d; int off;
    if (blk < 2048) { s = x; d = xb; off = blk; }
    else {
        int t = (blk - 2048) >> 7;
        off = (blk - 2048) & 127;
        s = (t == 0) ? Wq : (t == 1) ? Wk : (t == 2) ? Wv : Wo;
        d = (t == 0) ? wqb : (t == 1) ? wkb : (t == 2) ? wvb : wob;
    }
    size_t base = ((size_t)off * 256 + threadIdx.x) * 8;
    float4 a = *(const float4*)(s + base);
    float4 b = *(const float4*)(s + base + 4);
    u16x8 pk;
    pk[0] = f2bf(a.x); pk[1] = f2bf(a.y); pk[2] = f2bf(a.z); pk[3] = f2bf(a.w);
    pk[4] = f2bf(b.x); pk[5] = f2bf(b.y); pk[6] = f2bf(b.z); pk[7] = f2bf(b.w);
    *(u16x8*)(d + base) = pk;
}

// ---------------- QKV projection GEMM, bf16 MFMA ------------
__global__ __launch_bounds__(256) void qkv_gemm_kernel(
    const unsigned short* __restrict__ xb, const unsigned short* __restrict__ Wqb,
    const unsigned short* __restrict__ Wkb, const unsigned short* __restrict__ Wvb,
    unsigned short* __restrict__ Qb, unsigned short* __restrict__ Kb,
    unsigned short* __restrict__ Vt)
{
    __shared__ unsigned short As[128 * 32];
    __shared__ unsigned short Bs[128 * 32];

    const int mt = blockIdx.x;
    const int nt = blockIdx.y;
    const int mbase = mt * 128;
    const int mat = nt >> 2;
    const unsigned short* W = (mat == 0) ? Wqb : ((mat == 1) ? Wkb : Wvb);
    const int nW = (nt & 3) * 128;

    const int tid = threadIdx.x;
    const int w = tid >> 6, lane = tid & 63;
    const int wr = w >> 1, wc = w & 1;
    const int l15 = lane & 15, koff = (lane >> 4) * 8;
    const int srow = (lane >> 2);
    const int scol = (lane & 3) * 8;

    f32x4 acc[4][4];
    #pragma unroll
    for (int i = 0; i < 4; ++i)
        #pragma unroll
        for (int j = 0; j < 4; ++j) acc[i][j] = (f32x4){0.f, 0.f, 0.f, 0.f};

    for (int kc = 0; kc < 512; kc += 32) {
        __syncthreads();
        #pragma unroll
        for (int j = 0; j < 2; ++j) {
            int row = w * 32 + j * 16;
            GLOAD_LDS16(xb + (size_t)(mbase + row + srow) * 512 + kc + scol,
                        As + row * 32);
            GLOAD_LDS16(W + (size_t)(nW + row + srow) * 512 + kc + scol,
                        Bs + row * 32);
        }
        __syncthreads();

        bf16x8 af[4], bf[4];
        #pragma unroll
        for (int mi = 0; mi < 4; ++mi)
            af[mi] = *(const bf16x8*)&As[(wr * 64 + mi * 16 + l15) * 32 + koff];
        #pragma unroll
        for (int ni = 0; ni < 4; ++ni)
            bf[ni] = *(const bf16x8*)&Bs[(wc * 64 + ni * 16 + l15) * 32 + koff];
        #pragma unroll
        for (int mi = 0; mi < 4; ++mi)
            #pragma unroll
            for (int ni = 0; ni < 4; ++ni)
                acc[mi][ni] = __builtin_amdgcn_mfma_f32_16x16x32_bf16(
                    af[mi], bf[ni], acc[mi][ni], 0, 0, 0);
    }

    const int h = (nt & 3) * 2 + wc;
    if (mat < 2) {
        unsigned short* D = (mat == 0) ? Qb : Kb;
        #pragma unroll
        for (int mi = 0; mi < 4; ++mi) {
            int m = mbase + wr * 64 + mi * 16 + (lane >> 4) * 4;
            int b = m >> 10, l0 = m & 1023;
            #pragma unroll
            for (int r = 0; r < 4; ++r) {
                size_t rowbase = ((size_t)(b * HH + h) * LL + l0 + r) * 64;
                #pragma unroll
                for (int ni = 0; ni < 4; ++ni)
                    D[rowbase + ni * 16 + l15] = f2bf(acc[mi][ni][r]);
            }
        }
    } else {
        #pragma unroll
        for (int mi = 0; mi < 4; ++mi) {
            int m = mbase + wr * 64 + mi * 16 + (lane >> 4) * 4;
            int b = m >> 10, l0 = m & 1023;
            #pragma unroll
            for (int ni = 0; ni < 4; ++ni) {
                int d = ni * 16 + l15;
                u16x4 pk;
                #pragma unroll
                for (int r = 0; r < 4; ++r) pk[r] = f2bf(acc[mi][ni][r]);
                *(u16x4*)(Vt + ((size_t)(b * HH + h) * 64 + d) * LL + l0) = pk;
            }
        }
    }
}

// ---------------- RoPE apply (Q gets 0.125*log2e folded for exp2 softmax) ---
__global__ __launch_bounds__(256) void rope_apply_kernel(
    unsigned short* __restrict__ q, unsigned short* __restrict__ k,
    const float* __restrict__ cos_t, const float* __restrict__ sin_t)
{
    int idx = blockIdx.x * blockDim.x + threadIdx.x;
    const int total = BB * HH * LL * 4;
    unsigned short* T = q;
    float sc = 0.125f * 1.44269504088896f;   // fold 1/sqrt(64) * log2(e)
    if (idx >= total) { T = k; idx -= total; sc = 1.0f; }
    int g = idx & 3;
    int bhl = idx >> 2;
    int l = bhl & (LL - 1);
    int j0 = g * 8;
    size_t base = (size_t)bhl * 64 + j0;
    u16x8 v0 = *(u16x8*)(T + base);
    u16x8 v1 = *(u16x8*)(T + base + 32);
    float4 c0 = *(const float4*)(cos_t + l * 32 + j0);
    float4 c1 = *(const float4*)(cos_t + l * 32 + j0 + 4);
    float4 s0 = *(const float4*)(sin_t + l * 32 + j0);
    float4 s1 = *(const float4*)(sin_t + l * 32 + j0 + 4);
    float cs[8] = {c0.x, c0.y, c0.z, c0.w, c1.x, c1.y, c1.z, c1.w};
    float sn[8] = {s0.x, s0.y, s0.z, s0.w, s1.x, s1.y, s1.z, s1.w};
    u16x8 o0, o1;
    #pragma unroll
    for (int i = 0; i < 8; ++i) {
        float x0 = bf2f(v0[i]), x1 = bf2f(v1[i]);
        o0[i] = f2bf((x0 * cs[i] - x1 * sn[i]) * sc);
        o1[i] = f2bf((x1 * cs[i] + x0 * sn[i]) * sc);
    }
    *(u16x8*)(T + base)      = o0;
    *(u16x8*)(T + base + 32) = o1;
}

// ---------------- Flash attention: swapped QK^T, per-lane softmax -----------
// Wave w owns q-rows [qt*64 + w*16, +16); lane's q-row = q0 + (lane&15).
// s[nt] = mfma(K_frag, Q_frag): rows=k, cols=q  ->  lane holds 16 k-values
// of ONE q-row. Softmax: 15 local max/adds + shfl_xor(16) + shfl_xor(32).
__global__ __launch_bounds__(256) void attn_kernel(
    const unsigned short* __restrict__ Q, const unsigned short* __restrict__ K,
    const unsigned short* __restrict__ Vt, unsigned short* __restrict__ O)
{
    __shared__ unsigned short Plds[4][16][72];   // [wave][q=16][k=64] stride 72

    const int qt = blockIdx.x;      // 0..15
    const int bh = blockIdx.y;      // 0..63
    const int b = bh >> 3, h = bh & 7;
    const int tid = threadIdx.x;
    const int w = tid >> 6;
    const int lane = tid & 63;
    const int l15 = lane & 15;
    const int g4 = (lane >> 4) * 4;
    const int koff = (lane >> 4) * 8;

    const unsigned short* Qp = Q + (size_t)bh * LL * 64;
    const unsigned short* Kp = K + (size_t)bh * LL * 64;
    const unsigned short* Vp = Vt + (size_t)bh * 64 * LL;

    const int q0 = qt * 64 + w * 16;

    // Q as B-fragment: col=q=l15, k=d
    bf16x8 qf0 = *(const bf16x8*)(Qp + (size_t)(q0 + l15) * 64 + koff);
    bf16x8 qf1 = *(const bf16x8*)(Qp + (size_t)(q0 + l15) * 64 + koff + 32);

    float m_i = -1e30f, l_i = 0.f;
    f32x4 opv[4];                   // O^T: row=d (dt*16+g4+r), col=q=l15
    #pragma unroll
    for (int dt = 0; dt < 4; ++dt) opv[dt] = (f32x4){0.f, 0.f, 0.f, 0.f};

    // prologue: K fragments for kt=0 (A-frag: row=k, k-dim=d)
    bf16x8 kf[2][8];
    #pragma unroll
    for (int nt = 0; nt < 4; ++nt) {
        const unsigned short* kp = Kp + (size_t)(nt * 16 + l15) * 64 + koff;
        kf[0][2 * nt]     = *(const bf16x8*)kp;
        kf[0][2 * nt + 1] = *(const bf16x8*)(kp + 32);
    }

    #pragma unroll 2
    for (int kt = 0; kt < 16; ++kt) {
        const int cur = kt & 1, nxt = cur ^ 1;
        const int kbase = kt * 64;

        // S^T = K Q^T : lane holds k = nt*16+g4+r (rows), q = l15 (col)
        f32x4 s[4];
        __builtin_amdgcn_s_setprio(1);
        #pragma unroll
        for (int nt = 0; nt < 4; ++nt) {
            f32x4 z = {0.f, 0.f, 0.f, 0.f};
            z = __builtin_amdgcn_mfma_f32_16x16x32_bf16(kf[cur][2 * nt],     qf0, z, 0, 0, 0);
            z = __builtin_amdgcn_mfma_f32_16x16x32_bf16(kf[cur][2 * nt + 1], qf1, z, 0, 0, 0);
            s[nt] = z;
        }
        __builtin_amdgcn_s_setprio(0);

        // prefetch next tile's K fragments (issue early; consumed next iter)
        const int nkb = (kt < 15) ? kbase + 64 : 0;
        #pragma unroll
        for (int nt = 0; nt < 4; ++nt) {
            const unsigned short* kp = Kp + (size_t)(nkb + nt * 16 + l15) * 64 + koff;
            kf[nxt][2 * nt]     = *(const bf16x8*)kp;
            kf[nxt][2 * nt + 1] = *(const bf16x8*)(kp + 32);
        }
        // V fragments for current tile (A-frag: row=d, k-dim=k)
        bf16x8 vf[8];
        #pragma unroll
        for (int dt = 0; dt < 4; ++dt) {
            const unsigned short* vp = Vp + (size_t)(dt * 16 + l15) * LL + kbase + koff;
            vf[2 * dt]     = *(const bf16x8*)vp;
            vf[2 * dt + 1] = *(const bf16x8*)(vp + 32);
        }

        // per-lane softmax over 16 local k-values + 2 cross-lane steps
        float m0 = fmaxf(fmaxf(s[0][0], s[0][1]), fmaxf(s[0][2], s[0][3]));
        float m1 = fmaxf(fmaxf(s[1][0], s[1][1]), fmaxf(s[1][2], s[1][3]));
        float m2 = fmaxf(fmaxf(s[2][0], s[2][1]), fmaxf(s[2][2], s[2][3]));
        float m3 = fmaxf(fmaxf(s[3][0], s[3][1]), fmaxf(s[3][2], s[3][3]));
        float mx = fmaxf(fmaxf(m0, m1), fmaxf(m2, m3));
        mx = fmaxf(mx, __shfl_xor(mx, 16));
        mx = fmaxf(mx, __shfl_xor(mx, 32));
        float mnew = fmaxf(m_i, mx);
        float alpha = exp2f(m_i - mnew);
        m_i = mnew;

        float rs = 0.f;
        #pragma unroll
        for (int nt = 0; nt < 4; ++nt) {
            float p0 = exp2f(s[nt][0] - mnew);
            float p1 = exp2f(s[nt][1] - mnew);
            float p2 = exp2f(s[nt][2] - mnew);
            float p3 = exp2f(s[nt][3] - mnew);
            rs += (p0 + p1) + (p2 + p3);
            u16x4 pk;
            pk[0] = f2bf(p0); pk[1] = f2bf(p1); pk[2] = f2bf(p2); pk[3] = f2bf(p3);
            *(u16x4*)&Plds[w][l15][nt * 16 + g4] = pk;
        }
        rs += __shfl_xor(rs, 16);
        rs += __shfl_xor(rs, 32);
        l_i = l_i * alpha + rs;

        #pragma unroll
        for (int dt = 0; dt < 4; ++dt)
            #pragma unroll
            for (int r = 0; r < 4; ++r) opv[dt][r] *= alpha;

        // P^T as B-fragment from LDS (col=q=l15, k contiguous)
        bf16x8 pf0 = *(const bf16x8*)&Plds[w][l15][koff];
        bf16x8 pf1 = *(const bf16x8*)&Plds[w][l15][koff + 32];

        // O^T += V^T P^T
        __builtin_amdgcn_s_setprio(1);
        #pragma unroll
        for (int dt = 0; dt < 4; ++dt) {
            opv[dt] = __builtin_amdgcn_mfma_f32_16x16x32_bf16(vf[2 * dt],     pf0, opv[dt], 0, 0, 0);
            opv[dt] = __builtin_amdgcn_mfma_f32_16x16x32_bf16(vf[2 * dt + 1], pf1, opv[dt], 0, 0, 0);
        }
        __builtin_amdgcn_s_setprio(0);
    }

    // epilogue: lane owns q-row l=q0+l15, d = dt*16 + g4 + r
    const float inv = 1.f / l_i;
    const int l = q0 + l15;
    #pragma unroll
    for (int dt = 0; dt < 4; ++dt) {
        u16x4 pk;
        #pragma unroll
        for (int r = 0; r < 4; ++r) pk[r] = f2bf(opv[dt][r] * inv);
        *(u16x4*)(O + (size_t)(b * LL + l) * HID + h * 64 + dt * 16 + g4) = pk;
    }
}

// ---------------- Output projection GEMM, bf16 MFMA --------------------------
__global__ __launch_bounds__(256) void out_gemm_kernel(
    const unsigned short* __restrict__ AOb, const unsigned short* __restrict__ Wob,
    float* __restrict__ out)
{
    __shared__ unsigned short As[128 * 32];
    __shared__ unsigned short Bs[128 * 32];

    const int mt = blockIdx.x;
    const int nt = blockIdx.y;
    const int mbase = mt * 128;
    const int nbase = nt * 128;

    const int tid = threadIdx.x;
    const int w = tid >> 6, lane = tid & 63;
    const int wr = w >> 1, wc = w & 1;
    const int l15 = lane & 15, koff = (lane >> 4) * 8;
    const int srow = (lane >> 2);
    const int scol = (lane & 3) * 8;

    f32x4 acc[4][4];
    #pragma unroll
    for (int i = 0; i < 4; ++i)
        #pragma unroll
        for (int j = 0; j < 4; ++j) acc[i][j] = (f32x4){0.f, 0.f, 0.f, 0.f};

    for (int kc = 0; kc < 512; kc += 32) {
        __syncthreads();
        #pragma unroll
        for (int j = 0; j < 2; ++j) {
            int row = w * 32 + j * 16;
            GLOAD_LDS16(AOb + (size_t)(mbase + row + srow) * 512 + kc + scol,
                        As + row * 32);
            GLOAD_LDS16(Wob + (size_t)(nbase + row + srow) * 512 + kc + scol,
                        Bs + row * 32);
        }
        __syncthreads();

        bf16x8 af[4], bf[4];
        #pragma unroll
        for (int mi = 0; mi < 4; ++mi)
            af[mi] = *(const bf16x8*)&As[(wr * 64 + mi * 16 + l15) * 32 + koff];
        #pragma unroll
        for (int ni = 0; ni < 4; ++ni)
            bf[ni] = *(const bf16x8*)&Bs[(wc * 64 + ni * 16 + l15) * 32 + koff];
        #pragma unroll
        for (int mi = 0; mi < 4; ++mi)
            #pragma unroll
            for (int ni = 0; ni < 4; ++ni)
                acc[mi][ni] = __builtin_amdgcn_mfma_f32_16x16x32_bf16(
                    af[mi], bf[ni], acc[mi][ni], 0, 0, 0);
    }

    #pragma unroll
    for (int mi = 0; mi < 4; ++mi) {
        int m = mbase + wr * 64 + mi * 16 + (lane >> 4) * 4;
        #pragma unroll
        for (int r = 0; r < 4; ++r) {
            size_t rowbase = (size_t)(m + r) * 512 + nbase + wc * 64;
            #pragma unroll
            for (int ni = 0; ni < 4; ++ni)
                out[rowbase + ni * 16 + l15] = acc[mi][ni][r];
        }
    }
}

extern "C" void kernel_launch(void* const* d_in, const int* in_sizes, int n_in,
                              void* d_out, int out_size, void* d_ws, size_t ws_size,
                              hipStream_t stream) {
    const float* x  = (const float*)d_in[0];
    const float* Wq = (const float*)d_in[1];
    const float* Wk = (const float*)d_in[2];
    const float* Wv = (const float*)d_in[3];
    const float* Wo = (const float*)d_in[4];
    float* out = (float*)d_out;

    const size_t tblN = (size_t)LL * 32;
    const size_t qkvN = (size_t)BB * HH * LL * 64;
    const size_t wN   = (size_t)HID * HID;

    float* cos_t = (float*)d_ws;
    float* sin_t = cos_t + tblN;
    unsigned short* Qb  = (unsigned short*)(sin_t + tblN);
    unsigned short* Kb  = Qb + qkvN;
    unsigned short* Vt  = Kb + qkvN;
    unsigned short* xb  = Vt + qkvN;
    unsigned short* Wqb = xb + qkvN;
    unsigned short* Wkb = Wqb + wN;
    unsigned short* Wvb = Wkb + wN;
    unsigned short* Wob = Wvb + wN;
    unsigned short* AOb = Wob + wN;

    hipLaunchKernelGGL(rope_table_kernel, dim3((LL * 32 + 255) / 256), dim3(256), 0, stream,
                       cos_t, sin_t);
    hipLaunchKernelGGL(convert_kernel, dim3(2048 + 512), dim3(256), 0, stream,
                       x, Wq, Wk, Wv, Wo, xb, Wqb, Wkb, Wvb, Wob);
    hipLaunchKernelGGL(qkv_gemm_kernel, dim3(64, 12), dim3(256), 0, stream,
                       xb, Wqb, Wkb, Wvb, Qb, Kb, Vt);
    hipLaunchKernelGGL(rope_apply_kernel, dim3((2 * BB * HH * LL * 4) / 256), dim3(256), 0, stream,
                       Qb, Kb, cos_t, sin_t);
    hipLaunchKernelGGL(attn_kernel, dim3(16, 64), dim3(256), 0, stream,
                       Qb, Kb, Vt, AOb);
    hipLaunchKernelGGL(out_gemm_kernel, dim3(64, 4), dim3(256), 0, stream,
                       AOb, Wob, out);
}

// Round 5
// 186.234 us; speedup vs baseline: 1.0017x; 1.0017x over previous
//
#include <hip/hip_runtime.h>
#include <math.h>

// RoPE+SDPA attention. Round 4: XCD-aware block swizzle in attn (each XCD
// owns 8 heads -> K/V L2-resident, 2MB/XCD). Attn otherwise identical to R3.
// B=8 L=1024 H=8 Dh=64 HID=512.

#define BB 8
#define LL 1024
#define HH 8
#define DH 64
#define HID 512

typedef __bf16 bf16x8 __attribute__((ext_vector_type(8)));
typedef float f32x4 __attribute__((ext_vector_type(4)));
typedef unsigned short u16x8 __attribute__((ext_vector_type(8)));
typedef unsigned short u16x4 __attribute__((ext_vector_type(4)));

__device__ inline unsigned short f2bf(float f) {
    union { float f; unsigned u; } v; v.f = f;
    unsigned r = v.u + 0x7fffu + ((v.u >> 16) & 1u);
    return (unsigned short)(r >> 16);
}
__device__ inline float bf2f(unsigned short s) {
    union { unsigned u; float f; } v; v.u = ((unsigned)s) << 16;
    return v.f;
}

#define GLOAD_LDS16(g, l) __builtin_amdgcn_global_load_lds( \
    (const __attribute__((address_space(1))) unsigned int*)(g), \
    (__attribute__((address_space(3))) unsigned int*)(l), 16, 0, 0)

// ---------------- RoPE table ----------------
__global__ void rope_table_kernel(float* __restrict__ cos_t, float* __restrict__ sin_t) {
    int idx = blockIdx.x * blockDim.x + threadIdx.x;
    if (idx >= LL * 32) return;
    int l = idx >> 5, j = idx & 31;
    float inv = exp2f(-(float)j * (13.287712379549449f / 32.0f));
    float th = (float)l * inv;
    cos_t[idx] = cosf(th);
    sin_t[idx] = sinf(th);
}

// ---------------- fp32 -> bf16 convert (x and the four W's) ----------------
__global__ __launch_bounds__(256) void convert_kernel(
    const float* __restrict__ x, const float* __restrict__ Wq,
    const float* __restrict__ Wk, const float* __restrict__ Wv,
    const float* __restrict__ Wo,
    unsigned short* __restrict__ xb, unsigned short* __restrict__ wqb,
    unsigned short* __restrict__ wkb, unsigned short* __restrict__ wvb,
    unsigned short* __restrict__ wob)
{
    int blk = blockIdx.x;
    const float* s; unsigned short* d; int off;
    if (blk < 2048) { s = x; d = xb; off = blk; }
    else {
        int t = (blk - 2048) >> 7;
        off = (blk - 2048) & 127;
        s = (t == 0) ? Wq : (t == 1) ? Wk : (t == 2) ? Wv : Wo;
        d = (t == 0) ? wqb : (t == 1) ? wkb : (t == 2) ? wvb : wob;
    }
    size_t base = ((size_t)off * 256 + threadIdx.x) * 8;
    float4 a = *(const float4*)(s + base);
    float4 b = *(const float4*)(s + base + 4);
    u16x8 pk;
    pk[0] = f2bf(a.x); pk[1] = f2bf(a.y); pk[2] = f2bf(a.z); pk[3] = f2bf(a.w);
    pk[4] = f2bf(b.x); pk[5] = f2bf(b.y); pk[6] = f2bf(b.z); pk[7] = f2bf(b.w);
    *(u16x8*)(d + base) = pk;
}

// ---------------- QKV projection GEMM, bf16 MFMA ------------
__global__ __launch_bounds__(256) void qkv_gemm_kernel(
    const unsigned short* __restrict__ xb, const unsigned short* __restrict__ Wqb,
    const unsigned short* __restrict__ Wkb, const unsigned short* __restrict__ Wvb,
    unsigned short* __restrict__ Qb, unsigned short* __restrict__ Kb,
    unsigned short* __restrict__ Vt)
{
    __shared__ unsigned short As[128 * 32];
    __shared__ unsigned short Bs[128 * 32];

    const int mt = blockIdx.x;
    const int nt = blockIdx.y;
    const int mbase = mt * 128;
    const int mat = nt >> 2;
    const unsigned short* W = (mat == 0) ? Wqb : ((mat == 1) ? Wkb : Wvb);
    const int nW = (nt & 3) * 128;

    const int tid = threadIdx.x;
    const int w = tid >> 6, lane = tid & 63;
    const int wr = w >> 1, wc = w & 1;
    const int l15 = lane & 15, koff = (lane >> 4) * 8;
    const int srow = (lane >> 2);
    const int scol = (lane & 3) * 8;

    f32x4 acc[4][4];
    #pragma unroll
    for (int i = 0; i < 4; ++i)
        #pragma unroll
        for (int j = 0; j < 4; ++j) acc[i][j] = (f32x4){0.f, 0.f, 0.f, 0.f};

    for (int kc = 0; kc < 512; kc += 32) {
        __syncthreads();
        #pragma unroll
        for (int j = 0; j < 2; ++j) {
            int row = w * 32 + j * 16;
            GLOAD_LDS16(xb + (size_t)(mbase + row + srow) * 512 + kc + scol,
                        As + row * 32);
            GLOAD_LDS16(W + (size_t)(nW + row + srow) * 512 + kc + scol,
                        Bs + row * 32);
        }
        __syncthreads();

        bf16x8 af[4], bf[4];
        #pragma unroll
        for (int mi = 0; mi < 4; ++mi)
            af[mi] = *(const bf16x8*)&As[(wr * 64 + mi * 16 + l15) * 32 + koff];
        #pragma unroll
        for (int ni = 0; ni < 4; ++ni)
            bf[ni] = *(const bf16x8*)&Bs[(wc * 64 + ni * 16 + l15) * 32 + koff];
        #pragma unroll
        for (int mi = 0; mi < 4; ++mi)
            #pragma unroll
            for (int ni = 0; ni < 4; ++ni)
                acc[mi][ni] = __builtin_amdgcn_mfma_f32_16x16x32_bf16(
                    af[mi], bf[ni], acc[mi][ni], 0, 0, 0);
    }

    const int h = (nt & 3) * 2 + wc;
    if (mat < 2) {
        unsigned short* D = (mat == 0) ? Qb : Kb;
        #pragma unroll
        for (int mi = 0; mi < 4; ++mi) {
            int m = mbase + wr * 64 + mi * 16 + (lane >> 4) * 4;
            int b = m >> 10, l0 = m & 1023;
            #pragma unroll
            for (int r = 0; r < 4; ++r) {
                size_t rowbase = ((size_t)(b * HH + h) * LL + l0 + r) * 64;
                #pragma unroll
                for (int ni = 0; ni < 4; ++ni)
                    D[rowbase + ni * 16 + l15] = f2bf(acc[mi][ni][r]);
            }
        }
    } else {
        #pragma unroll
        for (int mi = 0; mi < 4; ++mi) {
            int m = mbase + wr * 64 + mi * 16 + (lane >> 4) * 4;
            int b = m >> 10, l0 = m & 1023;
            #pragma unroll
            for (int ni = 0; ni < 4; ++ni) {
                int d = ni * 16 + l15;
                u16x4 pk;
                #pragma unroll
                for (int r = 0; r < 4; ++r) pk[r] = f2bf(acc[mi][ni][r]);
                *(u16x4*)(Vt + ((size_t)(b * HH + h) * 64 + d) * LL + l0) = pk;
            }
        }
    }
}

// ---------------- RoPE apply (Q gets 0.125*log2e folded for exp2 softmax) ---
__global__ __launch_bounds__(256) void rope_apply_kernel(
    unsigned short* __restrict__ q, unsigned short* __restrict__ k,
    const float* __restrict__ cos_t, const float* __restrict__ sin_t)
{
    int idx = blockIdx.x * blockDim.x + threadIdx.x;
    const int total = BB * HH * LL * 4;
    unsigned short* T = q;
    float sc = 0.125f * 1.44269504088896f;
    if (idx >= total) { T = k; idx -= total; sc = 1.0f; }
    int g = idx & 3;
    int bhl = idx >> 2;
    int l = bhl & (LL - 1);
    int j0 = g * 8;
    size_t base = (size_t)bhl * 64 + j0;
    u16x8 v0 = *(u16x8*)(T + base);
    u16x8 v1 = *(u16x8*)(T + base + 32);
    float4 c0 = *(const float4*)(cos_t + l * 32 + j0);
    float4 c1 = *(const float4*)(cos_t + l * 32 + j0 + 4);
    float4 s0 = *(const float4*)(sin_t + l * 32 + j0);
    float4 s1 = *(const float4*)(sin_t + l * 32 + j0 + 4);
    float cs[8] = {c0.x, c0.y, c0.z, c0.w, c1.x, c1.y, c1.z, c1.w};
    float sn[8] = {s0.x, s0.y, s0.z, s0.w, s1.x, s1.y, s1.z, s1.w};
    u16x8 o0, o1;
    #pragma unroll
    for (int i = 0; i < 8; ++i) {
        float x0 = bf2f(v0[i]), x1 = bf2f(v1[i]);
        o0[i] = f2bf((x0 * cs[i] - x1 * sn[i]) * sc);
        o1[i] = f2bf((x1 * cs[i] + x0 * sn[i]) * sc);
    }
    *(u16x8*)(T + base)      = o0;
    *(u16x8*)(T + base + 32) = o1;
}

// ---------------- Flash attention: swapped QK^T + XCD-aware placement -------
// 1-D grid of 1024 blocks. wgid%8 = XCD (HW round-robin); each XCD gets
// 8 heads' worth of blocks -> per-XCD K/V working set = 2MB, L2-resident.
__global__ __launch_bounds__(256) void attn_kernel(
    const unsigned short* __restrict__ Q, const unsigned short* __restrict__ K,
    const unsigned short* __restrict__ Vt, unsigned short* __restrict__ O)
{
    __shared__ unsigned short Plds[4][16][72];   // [wave][q=16][k=64] stride 72

    const int wgid = blockIdx.x;    // 0..1023
    const int xcd = wgid & 7;
    const int j = wgid >> 3;        // 0..127
    const int bh = xcd * 8 + (j >> 4);
    const int qt = j & 15;
    const int b = bh >> 3, h = bh & 7;
    const int tid = threadIdx.x;
    const int w = tid >> 6;
    const int lane = tid & 63;
    const int l15 = lane & 15;
    const int g4 = (lane >> 4) * 4;
    const int koff = (lane >> 4) * 8;

    const unsigned short* Qp = Q + (size_t)bh * LL * 64;
    const unsigned short* Kp = K + (size_t)bh * LL * 64;
    const unsigned short* Vp = Vt + (size_t)bh * 64 * LL;

    const int q0 = qt * 64 + w * 16;

    // Q as B-fragment: col=q=l15, k=d
    bf16x8 qf0 = *(const bf16x8*)(Qp + (size_t)(q0 + l15) * 64 + koff);
    bf16x8 qf1 = *(const bf16x8*)(Qp + (size_t)(q0 + l15) * 64 + koff + 32);

    float m_i = -1e30f, l_i = 0.f;
    f32x4 opv[4];                   // O^T: row=d (dt*16+g4+r), col=q=l15
    #pragma unroll
    for (int dt = 0; dt < 4; ++dt) opv[dt] = (f32x4){0.f, 0.f, 0.f, 0.f};

    // prologue: K fragments for kt=0 (A-frag: row=k, k-dim=d)
    bf16x8 kf[2][8];
    #pragma unroll
    for (int nt = 0; nt < 4; ++nt) {
        const unsigned short* kp = Kp + (size_t)(nt * 16 + l15) * 64 + koff;
        kf[0][2 * nt]     = *(const bf16x8*)kp;
        kf[0][2 * nt + 1] = *(const bf16x8*)(kp + 32);
    }

    #pragma unroll 2
    for (int kt = 0; kt < 16; ++kt) {
        const int cur = kt & 1, nxt = cur ^ 1;
        const int kbase = kt * 64;

        // S^T = K Q^T : lane holds k = nt*16+g4+r (rows), q = l15 (col)
        f32x4 s[4];
        __builtin_amdgcn_s_setprio(1);
        #pragma unroll
        for (int nt = 0; nt < 4; ++nt) {
            f32x4 z = {0.f, 0.f, 0.f, 0.f};
            z = __builtin_amdgcn_mfma_f32_16x16x32_bf16(kf[cur][2 * nt],     qf0, z, 0, 0, 0);
            z = __builtin_amdgcn_mfma_f32_16x16x32_bf16(kf[cur][2 * nt + 1], qf1, z, 0, 0, 0);
            s[nt] = z;
        }
        __builtin_amdgcn_s_setprio(0);

        // prefetch next tile's K fragments (issue early; consumed next iter)
        const int nkb = (kt < 15) ? kbase + 64 : 0;
        #pragma unroll
        for (int nt = 0; nt < 4; ++nt) {
            const unsigned short* kp = Kp + (size_t)(nkb + nt * 16 + l15) * 64 + koff;
            kf[nxt][2 * nt]     = *(const bf16x8*)kp;
            kf[nxt][2 * nt + 1] = *(const bf16x8*)(kp + 32);
        }
        // V fragments for current tile (A-frag: row=d, k-dim=k)
        bf16x8 vf[8];
        #pragma unroll
        for (int dt = 0; dt < 4; ++dt) {
            const unsigned short* vp = Vp + (size_t)(dt * 16 + l15) * LL + kbase + koff;
            vf[2 * dt]     = *(const bf16x8*)vp;
            vf[2 * dt + 1] = *(const bf16x8*)(vp + 32);
        }

        // per-lane softmax over 16 local k-values + 2 cross-lane steps
        float m0 = fmaxf(fmaxf(s[0][0], s[0][1]), fmaxf(s[0][2], s[0][3]));
        float m1 = fmaxf(fmaxf(s[1][0], s[1][1]), fmaxf(s[1][2], s[1][3]));
        float m2 = fmaxf(fmaxf(s[2][0], s[2][1]), fmaxf(s[2][2], s[2][3]));
        float m3 = fmaxf(fmaxf(s[3][0], s[3][1]), fmaxf(s[3][2], s[3][3]));
        float mx = fmaxf(fmaxf(m0, m1), fmaxf(m2, m3));
        mx = fmaxf(mx, __shfl_xor(mx, 16));
        mx = fmaxf(mx, __shfl_xor(mx, 32));
        float mnew = fmaxf(m_i, mx);
        float alpha = exp2f(m_i - mnew);
        m_i = mnew;

        float rs = 0.f;
        #pragma unroll
        for (int nt = 0; nt < 4; ++nt) {
            float p0 = exp2f(s[nt][0] - mnew);
            float p1 = exp2f(s[nt][1] - mnew);
            float p2 = exp2f(s[nt][2] - mnew);
            float p3 = exp2f(s[nt][3] - mnew);
            rs += (p0 + p1) + (p2 + p3);
            u16x4 pk;
            pk[0] = f2bf(p0); pk[1] = f2bf(p1); pk[2] = f2bf(p2); pk[3] = f2bf(p3);
            *(u16x4*)&Plds[w][l15][nt * 16 + g4] = pk;
        }
        rs += __shfl_xor(rs, 16);
        rs += __shfl_xor(rs, 32);
        l_i = l_i * alpha + rs;

        #pragma unroll
        for (int dt = 0; dt < 4; ++dt)
            #pragma unroll
            for (int r = 0; r < 4; ++r) opv[dt][r] *= alpha;

        // P^T as B-fragment from LDS (col=q=l15, k contiguous)
        bf16x8 pf0 = *(const bf16x8*)&Plds[w][l15][koff];
        bf16x8 pf1 = *(const bf16x8*)&Plds[w][l15][koff + 32];

        // O^T += V^T P^T
        __builtin_amdgcn_s_setprio(1);
        #pragma unroll
        for (int dt = 0; dt < 4; ++dt) {
            opv[dt] = __builtin_amdgcn_mfma_f32_16x16x32_bf16(vf[2 * dt],     pf0, opv[dt], 0, 0, 0);
            opv[dt] = __builtin_amdgcn_mfma_f32_16x16x32_bf16(vf[2 * dt + 1], pf1, opv[dt], 0, 0, 0);
        }
        __builtin_amdgcn_s_setprio(0);
    }

    // epilogue: lane owns q-row l=q0+l15, d = dt*16 + g4 + r
    const float inv = 1.f / l_i;
    const int l = q0 + l15;
    #pragma unroll
    for (int dt = 0; dt < 4; ++dt) {
        u16x4 pk;
        #pragma unroll
        for (int r = 0; r < 4; ++r) pk[r] = f2bf(opv[dt][r] * inv);
        *(u16x4*)(O + (size_t)(b * LL + l) * HID + h * 64 + dt * 16 + g4) = pk;
    }
}

// ---------------- Output projection GEMM, bf16 MFMA --------------------------
__global__ __launch_bounds__(256) void out_gemm_kernel(
    const unsigned short* __restrict__ AOb, const unsigned short* __restrict__ Wob,
    float* __restrict__ out)
{
    __shared__ unsigned short As[128 * 32];
    __shared__ unsigned short Bs[128 * 32];

    const int mt = blockIdx.x;
    const int nt = blockIdx.y;
    const int mbase = mt * 128;
    const int nbase = nt * 128;

    const int tid = threadIdx.x;
    const int w = tid >> 6, lane = tid & 63;
    const int wr = w >> 1, wc = w & 1;
    const int l15 = lane & 15, koff = (lane >> 4) * 8;
    const int srow = (lane >> 2);
    const int scol = (lane & 3) * 8;

    f32x4 acc[4][4];
    #pragma unroll
    for (int i = 0; i < 4; ++i)
        #pragma unroll
        for (int j = 0; j < 4; ++j) acc[i][j] = (f32x4){0.f, 0.f, 0.f, 0.f};

    for (int kc = 0; kc < 512; kc += 32) {
        __syncthreads();
        #pragma unroll
        for (int j = 0; j < 2; ++j) {
            int row = w * 32 + j * 16;
            GLOAD_LDS16(AOb + (size_t)(mbase + row + srow) * 512 + kc + scol,
                        As + row * 32);
            GLOAD_LDS16(Wob + (size_t)(nbase + row + srow) * 512 + kc + scol,
                        Bs + row * 32);
        }
        __syncthreads();

        bf16x8 af[4], bf[4];
        #pragma unroll
        for (int mi = 0; mi < 4; ++mi)
            af[mi] = *(const bf16x8*)&As[(wr * 64 + mi * 16 + l15) * 32 + koff];
        #pragma unroll
        for (int ni = 0; ni < 4; ++ni)
            bf[ni] = *(const bf16x8*)&Bs[(wc * 64 + ni * 16 + l15) * 32 + koff];
        #pragma unroll
        for (int mi = 0; mi < 4; ++mi)
            #pragma unroll
            for (int ni = 0; ni < 4; ++ni)
                acc[mi][ni] = __builtin_amdgcn_mfma_f32_16x16x32_bf16(
                    af[mi], bf[ni], acc[mi][ni], 0, 0, 0);
    }

    #pragma unroll
    for (int mi = 0; mi < 4; ++mi) {
        int m = mbase + wr * 64 + mi * 16 + (lane >> 4) * 4;
        #pragma unroll
        for (int r = 0; r < 4; ++r) {
            size_t rowbase = (size_t)(m + r) * 512 + nbase + wc * 64;
            #pragma unroll
            for (int ni = 0; ni < 4; ++ni)
                out[rowbase + ni * 16 + l15] = acc[mi][ni][r];
        }
    }
}

extern "C" void kernel_launch(void* const* d_in, const int* in_sizes, int n_in,
                              void* d_out, int out_size, void* d_ws, size_t ws_size,
                              hipStream_t stream) {
    const float* x  = (const float*)d_in[0];
    const float* Wq = (const float*)d_in[1];
    const float* Wk = (const float*)d_in[2];
    const float* Wv = (const float*)d_in[3];
    const float* Wo = (const float*)d_in[4];
    float* out = (float*)d_out;

    const size_t tblN = (size_t)LL * 32;
    const size_t qkvN = (size_t)BB * HH * LL * 64;
    const size_t wN   = (size_t)HID * HID;

    float* cos_t = (float*)d_ws;
    float* sin_t = cos_t + tblN;
    unsigned short* Qb  = (unsigned short*)(sin_t + tblN);
    unsigned short* Kb  = Qb + qkvN;
    unsigned short* Vt  = Kb + qkvN;
    unsigned short* xb  = Vt + qkvN;
    unsigned short* Wqb = xb + qkvN;
    unsigned short* Wkb = Wqb + wN;
    unsigned short* Wvb = Wkb + wN;
    unsigned short* Wob = Wvb + wN;
    unsigned short* AOb = Wob + wN;

    hipLaunchKernelGGL(rope_table_kernel, dim3((LL * 32 + 255) / 256), dim3(256), 0, stream,
                       cos_t, sin_t);
    hipLaunchKernelGGL(convert_kernel, dim3(2048 + 512), dim3(256), 0, stream,
                       x, Wq, Wk, Wv, Wo, xb, Wqb, Wkb, Wvb, Wob);
    hipLaunchKernelGGL(qkv_gemm_kernel, dim3(64, 12), dim3(256), 0, stream,
                       xb, Wqb, Wkb, Wvb, Qb, Kb, Vt);
    hipLaunchKernelGGL(rope_apply_kernel, dim3((2 * BB * HH * LL * 4) / 256), dim3(256), 0, stream,
                       Qb, Kb, cos_t, sin_t);
    hipLaunchKernelGGL(attn_kernel, dim3(1024), dim3(256), 0, stream,
                       Qb, Kb, Vt, AOb);
    hipLaunchKernelGGL(out_gemm_kernel, dim3(64, 4), dim3(256), 0, stream,
                       AOb, Wob, out);
}